// Round 7
// baseline (147.691 us; speedup 1.0000x reference)
//
#include <hip/hip_runtime.h>

#define NTOK 1024
#define DDIM 128

typedef _Float16 f16;
typedef _Float16 f16x2v __attribute__((ext_vector_type(2)));
typedef _Float16 f16x4 __attribute__((ext_vector_type(4)));
typedef _Float16 f16x8 __attribute__((ext_vector_type(8)));
typedef float f32x16 __attribute__((ext_vector_type(16)));
typedef unsigned int uint;
typedef long i64;

union AFrag {
  float f[2];
  f16x4 h;
};

#define AS1 __attribute__((address_space(1)))
#define AS3 __attribute__((address_space(3)))
#define NLOG2E -1.44269504f

// ---------------- fused prepass ---------------------------------------------
// blocks [0,1024):     x -> x8n (normalized fp8) + xhT (unscaled f16 transpose)
//                      64-row tiles, 4 blocks/CU, 3 shfl per row-chunk
// blocks [1024,1280):  beta -> betaTp f16 pairs [m>>1][i][2], pre-scaled -log2e
__global__ __launch_bounds__(256) void prep_fused(
    const float* __restrict__ x, const float* __restrict__ beta,
    unsigned char* __restrict__ x8n, f16* __restrict__ xhT,
    uint* __restrict__ betaTp) {
  __shared__ __align__(16) char psm[17408];
  int bx = blockIdx.x;
  int t = threadIdx.x;
  if (bx < 1024) {
    f16* sT = (f16*)psm;  // [64][132]
    int bc = bx & 63;
    int nt = bx >> 6;  // 0..15
    int n0 = nt * 64;
    const float4* xv = (const float4*)(x + ((size_t)bc * NTOK + n0) * DDIM);
    int rbase = t >> 3;       // 0..31
    int c16 = (t & 7) * 4;    // float4 index, 4 consecutive per thread
#pragma unroll
    for (int rr = 0; rr < 64; rr += 32) {
      int row = rbase + rr;
      float4 v0 = xv[(size_t)row * 32 + c16 + 0];
      float4 v1 = xv[(size_t)row * 32 + c16 + 1];
      float4 v2 = xv[(size_t)row * 32 + c16 + 2];
      float4 v3 = xv[(size_t)row * 32 + c16 + 3];
      float ss = v0.x * v0.x + v0.y * v0.y + v0.z * v0.z + v0.w * v0.w;
      ss += v1.x * v1.x + v1.y * v1.y + v1.z * v1.z + v1.w * v1.w;
      ss += v2.x * v2.x + v2.y * v2.y + v2.z * v2.z + v2.w * v2.w;
      ss += v3.x * v3.x + v3.y * v3.y + v3.z * v3.z + v3.w * v3.w;
      ss += __shfl_xor(ss, 1);
      ss += __shfl_xor(ss, 2);
      ss += __shfl_xor(ss, 4);
      float rn = (ss > 0.f) ? rsqrtf(ss) : 0.f;
      int4 p8;
      {
        int a;
        a = __builtin_amdgcn_cvt_pk_fp8_f32(v0.x * rn, v0.y * rn, 0, false);
        p8.x = __builtin_amdgcn_cvt_pk_fp8_f32(v0.z * rn, v0.w * rn, a, true);
        a = __builtin_amdgcn_cvt_pk_fp8_f32(v1.x * rn, v1.y * rn, 0, false);
        p8.y = __builtin_amdgcn_cvt_pk_fp8_f32(v1.z * rn, v1.w * rn, a, true);
        a = __builtin_amdgcn_cvt_pk_fp8_f32(v2.x * rn, v2.y * rn, 0, false);
        p8.z = __builtin_amdgcn_cvt_pk_fp8_f32(v2.z * rn, v2.w * rn, a, true);
        a = __builtin_amdgcn_cvt_pk_fp8_f32(v3.x * rn, v3.y * rn, 0, false);
        p8.w = __builtin_amdgcn_cvt_pk_fp8_f32(v3.z * rn, v3.w * rn, a, true);
      }
      *(int4*)(x8n + ((size_t)bc * NTOK + n0 + row) * DDIM + (t & 7) * 16) = p8;
      f16x8 h0 = {(f16)v0.x, (f16)v0.y, (f16)v0.z, (f16)v0.w,
                  (f16)v1.x, (f16)v1.y, (f16)v1.z, (f16)v1.w};
      f16x8 h1 = {(f16)v2.x, (f16)v2.y, (f16)v2.z, (f16)v2.w,
                  (f16)v3.x, (f16)v3.y, (f16)v3.z, (f16)v3.w};
      *(f16x8*)(sT + row * 132 + (t & 7) * 16) = h0;
      *(f16x8*)(sT + row * 132 + (t & 7) * 16 + 8) = h1;
    }
    __syncthreads();
    int dr = t >> 1;    // d: 0..127
    int half = t & 1;   // rows 0-31 / 32-63
    f16* dst = xhT + ((size_t)bc * DDIM + dr) * NTOK + n0 + 32 * half;
#pragma unroll
    for (int s = 0; s < 4; ++s) {
      f16x8 tmp;
#pragma unroll
      for (int j = 0; j < 8; ++j)
        tmp[j] = sT[(32 * half + s * 8 + j) * 132 + dr];
      *(f16x8*)(dst + s * 8) = tmp;
    }
  } else {
    float(*s)[65] = (float(*)[65])psm;
    int bb = bx - 1024;
    int bi = bb & 15;  // i tile
    int bj = bb >> 4;  // m tile
    int r = t >> 4;
    int c4 = (t & 15) * 4;
#pragma unroll
    for (int rr = 0; rr < 64; rr += 16) {
      float4 v = *(const float4*)(beta + (size_t)(bi * 64 + r + rr) * NTOK +
                                  bj * 64 + c4);
      s[r + rr][c4] = v.x;
      s[r + rr][c4 + 1] = v.y;
      s[r + rr][c4 + 2] = v.z;
      s[r + rr][c4 + 3] = v.w;
    }
    __syncthreads();
    int il = t & 63;
#pragma unroll
    for (int rr = 0; rr < 8; ++rr) {
      int m2 = (t >> 6) + 4 * rr;  // 0..31
      float b0 = s[il][2 * m2] * NLOG2E;
      float b1 = s[il][2 * m2 + 1] * NLOG2E;
      uint u = __builtin_bit_cast(uint, __builtin_amdgcn_cvt_pkrtz(b0, b1));
      betaTp[(size_t)(bj * 32 + m2) * NTOK + bi * 64 + il] = u;
    }
  }
}

// ---------------- main ------------------------------------------------------
// 512 blocks, 2/CU. GEMM1: fp8 32x32x16, S^T in regs. Sigmoid -> pk pairs feed
// GEMM2 (32x32x8 f16) DIRECTLY as A-operand (no cross-lane transpose). GEMM2
// B = xhT rows (lane=d) -> output O[i][d] register-direct coalesced stores.
// Beta double-buffered in regs, loaded one iter ahead.
__global__ __launch_bounds__(256, 2) void cos_att_main(
    const unsigned char* __restrict__ x8n, const f16* __restrict__ xhT,
    const uint* __restrict__ betaTp, float* __restrict__ out) {
  __shared__ __align__(16) char smem[49152];  // dbuf: 2 x (sXm8 8K + sXmT 16K)
  int bx = blockIdx.x;
  int bc = bx & 63;
  int qp = bx >> 6;
  int q0 = qp * 128;

  int t = threadIdx.x;
  int lane = t & 63;
  int w = t >> 6;
  int l31 = lane & 31;
  int hi = lane >> 5;
  int i_str = (w >> 1) * 32;
  int m_str = (w & 1) * 32;

  // Xq B-frags (fp8) for both q-subtiles (32 VGPRs)
  i64 xqA8[8], xqB8[8];
  {
    const unsigned char* baseA =
        x8n + ((size_t)bc * NTOK + q0 + i_str + l31) * DDIM + hi * 8;
    const unsigned char* baseB = baseA + (size_t)64 * DDIM;
#pragma unroll
    for (int kk = 0; kk < 8; ++kk) {
      xqA8[kk] = *(const i64*)(baseA + kk * 16);
      xqB8[kk] = *(const i64*)(baseB + kk * 16);
    }
  }

  auto stage = [&](int mi, int b) {
    int m0 = mi * 64;
    char* ldsm8 = smem + b * 24576;
    char* ldst = ldsm8 + 8192;
    {  // sXm8: 64 rows x 128B fp8, 16B-chunk XOR by (r&7)
      const unsigned char* gb8 = x8n + ((size_t)bc * NTOK + m0) * DDIM;
#pragma unroll
      for (int j = 0; j < 2; ++j) {
        int u = t + 256 * j;
        int r = u >> 3;
        int cp = u & 7;
        const unsigned char* gp =
            gb8 + (size_t)r * DDIM + ((cp ^ (r & 7)) * 16);
        __builtin_amdgcn_global_load_lds((const AS1 uint*)gp,
                                         (AS3 uint*)(ldsm8 + u * 16), 16, 0, 0);
      }
    }
    {  // sXmT: 128 rows x 128B f16, 16B-chunk XOR by (d&7)
      int lr = lane >> 3;
      int cp = lane & 7;
      const f16* gb = xhT + (size_t)bc * DDIM * NTOK + m0;
#pragma unroll
      for (int j = 0; j < 4; ++j) {
        int d = 32 * w + 8 * j + lr;
        int g = cp ^ (d & 7);
        const f16* gp = gb + (size_t)d * NTOK + g * 8;
        __builtin_amdgcn_global_load_lds(
            (const AS1 uint*)gp, (AS3 uint*)(ldst + (32 * w + 8 * j) * 128),
            16, 0, 0);
      }
    }
  };

  // beta double-buffer (regs): loaded one iteration ahead
  uint bvA[2][8], bvB[2][8];
  auto loadBeta = [&](int mi, int p) {
    const uint* bbase =
        betaTp + (size_t)((mi * 64 + m_str) >> 1) * NTOK + q0 + i_str + l31;
#pragma unroll
    for (int rp = 0; rp < 8; ++rp) {
      int m2l = (rp & 1) + 4 * (rp >> 1) + 2 * hi;
      bvA[p][rp] = bbase[(size_t)m2l * NTOK];
      bvB[p][rp] = bbase[(size_t)m2l * NTOK + 64];
    }
  };

  stage(0, 0);
  loadBeta(0, 0);

  f32x16 o[8];
#pragma unroll
  for (int dt = 0; dt < 8; ++dt)
#pragma unroll
    for (int z = 0; z < 16; ++z) o[dt][z] = 0.f;

#pragma unroll 2
  for (int mi = 0; mi < 16; ++mi) {
    int b = mi & 1;
    __syncthreads();  // drains DMA(mi) + beta(mi); prev reads of buf[1-b] done
    if (mi < 15) {
      stage(mi + 1, 1 - b);
      loadBeta(mi + 1, 1 - b);
    }

    const char* ldsm8 = smem + b * 24576;
    const char* ldst = ldsm8 + 8192;

    // GEMM1 (fp8): S^T[m][i] for both subtiles, shared A-frag
    f32x16 s0, s1;
#pragma unroll
    for (int z = 0; z < 16; ++z) {
      s0[z] = 0.f;
      s1[z] = 0.f;
    }
    {
      int rA = m_str + l31;
      const char* rowA = ldsm8 + rA * 128;
      int rx = rA & 7;
#pragma unroll
      for (int kk = 0; kk < 8; ++kk) {
        i64 a = *(const i64*)(rowA + ((kk ^ rx) * 16) + hi * 8);
        s0 = __builtin_amdgcn_mfma_f32_32x32x16_fp8_fp8(a, xqA8[kk], s0, 0, 0, 0);
        s1 = __builtin_amdgcn_mfma_f32_32x32x16_fp8_fp8(a, xqB8[kk], s1, 0, 0, 0);
      }
    }

    // sigmoid for both subtiles -> packed f16 pairs (these ARE the GEMM2
    // A-fragments: reg r=4c..4c+3 holds m = 8c+4*hi+{0..3})
    float pkA[8], pkB[8];
#pragma unroll
    for (int rp = 0; rp < 8; ++rp) {
      f16x2v bh = __builtin_bit_cast(f16x2v, bvA[b][rp]);
      float e0 = __builtin_amdgcn_exp2f((float)bh[0] * s0[2 * rp]);
      float e1 = __builtin_amdgcn_exp2f((float)bh[1] * s0[2 * rp + 1]);
      float p0 = __builtin_amdgcn_rcpf(1.0f + e0);
      float p1 = __builtin_amdgcn_rcpf(1.0f + e1);
      pkA[rp] = __builtin_bit_cast(float, __builtin_amdgcn_cvt_pkrtz(p0, p1));
    }
#pragma unroll
    for (int rp = 0; rp < 8; ++rp) {
      f16x2v bh = __builtin_bit_cast(f16x2v, bvB[b][rp]);
      float e0 = __builtin_amdgcn_exp2f((float)bh[0] * s1[2 * rp]);
      float e1 = __builtin_amdgcn_exp2f((float)bh[1] * s1[2 * rp + 1]);
      float p0 = __builtin_amdgcn_rcpf(1.0f + e0);
      float p1 = __builtin_amdgcn_rcpf(1.0f + e1);
      pkB[rp] = __builtin_bit_cast(float, __builtin_amdgcn_cvt_pkrtz(p0, p1));
    }

    // GEMM2 (32x32x8 f16): O[i][d] += P . XmT-rows; B-frags shared across subs
#pragma unroll
    for (int dt = 0; dt < 4; ++dt) {
      int d = dt * 32 + l31;
      const char* rowT = ldst + d * 128;
      int dx = d & 7;
#pragma unroll
      for (int c = 0; c < 4; ++c) {
        int g = (m_str >> 3) + c;
        f16x4 bfr = *(const f16x4*)(rowT + ((g ^ dx) * 16) + hi * 8);
        AFrag aA, aB;
        aA.f[0] = pkA[2 * c];
        aA.f[1] = pkA[2 * c + 1];
        aB.f[0] = pkB[2 * c];
        aB.f[1] = pkB[2 * c + 1];
        o[dt] = __builtin_amdgcn_mfma_f32_32x32x8f16(aA.h, bfr, o[dt], 0, 0, 0);
        o[4 + dt] =
            __builtin_amdgcn_mfma_f32_32x32x8f16(aB.h, bfr, o[4 + dt], 0, 0, 0);
      }
    }
  }

  // epilogue: odd waves (m_str=32) park partials in LDS; even waves add + store
  float* sO = (float*)smem;  // [64][128] f32 = 32 KB
#pragma unroll
  for (int sub = 0; sub < 2; ++sub) {
    __syncthreads();
    if (w & 1) {
#pragma unroll
      for (int dt = 0; dt < 4; ++dt)
#pragma unroll
        for (int r = 0; r < 16; ++r) {
          int il = i_str + (r & 3) + 8 * (r >> 2) + 4 * hi;
          sO[il * 128 + dt * 32 + l31] = o[sub * 4 + dt][r];
        }
    }
    __syncthreads();
    if (!(w & 1)) {
      float* og = out + ((size_t)bc * NTOK + q0 + sub * 64) * DDIM;
#pragma unroll
      for (int dt = 0; dt < 4; ++dt)
#pragma unroll
        for (int r = 0; r < 16; ++r) {
          int il = i_str + (r & 3) + 8 * (r >> 2) + 4 * hi;
          og[(size_t)il * DDIM + dt * 32 + l31] =
              o[sub * 4 + dt][r] + sO[il * 128 + dt * 32 + l31];
        }
    }
  }
}

extern "C" void kernel_launch(void* const* d_in, const int* in_sizes, int n_in,
                              void* d_out, int out_size, void* d_ws,
                              size_t ws_size, hipStream_t stream) {
  const float* x = (const float*)d_in[0];
  const float* beta = (const float*)d_in[1];
  float* out = (float*)d_out;

  char* ws = (char*)d_ws;
  unsigned char* x8n = (unsigned char*)ws;  // 8 MB
  f16* xhT = (f16*)(ws + (8 << 20));        // 16 MB
  uint* betaTp = (uint*)(ws + (24 << 20));  // 2 MB

  prep_fused<<<1280, 256, 0, stream>>>(x, beta, x8n, xhT, betaTp);
  cos_att_main<<<512, 256, 0, stream>>>(x8n, xhT, betaTp, out);
}

// Round 8
// 139.578 us; speedup vs baseline: 1.0581x; 1.0581x over previous
//
#include <hip/hip_runtime.h>

#define NTOK 1024
#define DDIM 128

typedef _Float16 f16;
typedef _Float16 f16x2v __attribute__((ext_vector_type(2)));
typedef _Float16 f16x4 __attribute__((ext_vector_type(4)));
typedef _Float16 f16x8 __attribute__((ext_vector_type(8)));
typedef float f32x16 __attribute__((ext_vector_type(16)));
typedef unsigned int uint;
typedef long i64;

union PFrag {
  float f[4];
  f16x8 h;
};

#define AS1 __attribute__((address_space(1)))
#define AS3 __attribute__((address_space(3)))
#define NLOG2E -1.44269504f

// ---------------- fused prepass ---------------------------------------------
// blocks [0,1024):     x -> x8n (normalized fp8) + xhT (unscaled f16 transpose)
// blocks [1024,1280):  beta -> betaTp f16 pairs [m>>1][i][2], pre-scaled -log2e
__global__ __launch_bounds__(256) void prep_fused(
    const float* __restrict__ x, const float* __restrict__ beta,
    unsigned char* __restrict__ x8n, f16* __restrict__ xhT,
    uint* __restrict__ betaTp) {
  __shared__ __align__(16) char psm[17408];
  int bx = blockIdx.x;
  int t = threadIdx.x;
  if (bx < 1024) {
    f16* sT = (f16*)psm;  // [64][132]
    int bc = bx & 63;
    int nt = bx >> 6;  // 0..15
    int n0 = nt * 64;
    const float4* xv = (const float4*)(x + ((size_t)bc * NTOK + n0) * DDIM);
    int rbase = t >> 3;     // 0..31
    int c16 = (t & 7) * 4;  // float4 index, 4 consecutive per thread
#pragma unroll
    for (int rr = 0; rr < 64; rr += 32) {
      int row = rbase + rr;
      float4 v0 = xv[(size_t)row * 32 + c16 + 0];
      float4 v1 = xv[(size_t)row * 32 + c16 + 1];
      float4 v2 = xv[(size_t)row * 32 + c16 + 2];
      float4 v3 = xv[(size_t)row * 32 + c16 + 3];
      float ss = v0.x * v0.x + v0.y * v0.y + v0.z * v0.z + v0.w * v0.w;
      ss += v1.x * v1.x + v1.y * v1.y + v1.z * v1.z + v1.w * v1.w;
      ss += v2.x * v2.x + v2.y * v2.y + v2.z * v2.z + v2.w * v2.w;
      ss += v3.x * v3.x + v3.y * v3.y + v3.z * v3.z + v3.w * v3.w;
      ss += __shfl_xor(ss, 1);
      ss += __shfl_xor(ss, 2);
      ss += __shfl_xor(ss, 4);
      float rn = (ss > 0.f) ? rsqrtf(ss) : 0.f;
      int4 p8;
      {
        int a;
        a = __builtin_amdgcn_cvt_pk_fp8_f32(v0.x * rn, v0.y * rn, 0, false);
        p8.x = __builtin_amdgcn_cvt_pk_fp8_f32(v0.z * rn, v0.w * rn, a, true);
        a = __builtin_amdgcn_cvt_pk_fp8_f32(v1.x * rn, v1.y * rn, 0, false);
        p8.y = __builtin_amdgcn_cvt_pk_fp8_f32(v1.z * rn, v1.w * rn, a, true);
        a = __builtin_amdgcn_cvt_pk_fp8_f32(v2.x * rn, v2.y * rn, 0, false);
        p8.z = __builtin_amdgcn_cvt_pk_fp8_f32(v2.z * rn, v2.w * rn, a, true);
        a = __builtin_amdgcn_cvt_pk_fp8_f32(v3.x * rn, v3.y * rn, 0, false);
        p8.w = __builtin_amdgcn_cvt_pk_fp8_f32(v3.z * rn, v3.w * rn, a, true);
      }
      *(int4*)(x8n + ((size_t)bc * NTOK + n0 + row) * DDIM + (t & 7) * 16) = p8;
      f16x8 h0 = {(f16)v0.x, (f16)v0.y, (f16)v0.z, (f16)v0.w,
                  (f16)v1.x, (f16)v1.y, (f16)v1.z, (f16)v1.w};
      f16x8 h1 = {(f16)v2.x, (f16)v2.y, (f16)v2.z, (f16)v2.w,
                  (f16)v3.x, (f16)v3.y, (f16)v3.z, (f16)v3.w};
      *(f16x8*)(sT + row * 132 + (t & 7) * 16) = h0;
      *(f16x8*)(sT + row * 132 + (t & 7) * 16 + 8) = h1;
    }
    __syncthreads();
    int dr = t >> 1;   // d: 0..127
    int half = t & 1;  // rows 0-31 / 32-63
    f16* dst = xhT + ((size_t)bc * DDIM + dr) * NTOK + n0 + 32 * half;
#pragma unroll
    for (int s = 0; s < 4; ++s) {
      f16x8 tmp;
#pragma unroll
      for (int j = 0; j < 8; ++j)
        tmp[j] = sT[(32 * half + s * 8 + j) * 132 + dr];
      *(f16x8*)(dst + s * 8) = tmp;
    }
  } else {
    float(*s)[65] = (float(*)[65])psm;
    int bb = bx - 1024;
    int bi = bb & 15;  // i tile
    int bj = bb >> 4;  // m tile
    int r = t >> 4;
    int c4 = (t & 15) * 4;
#pragma unroll
    for (int rr = 0; rr < 64; rr += 16) {
      float4 v = *(const float4*)(beta + (size_t)(bi * 64 + r + rr) * NTOK +
                                  bj * 64 + c4);
      s[r + rr][c4] = v.x;
      s[r + rr][c4 + 1] = v.y;
      s[r + rr][c4 + 2] = v.z;
      s[r + rr][c4 + 3] = v.w;
    }
    __syncthreads();
    int il = t & 63;
#pragma unroll
    for (int rr = 0; rr < 8; ++rr) {
      int m2 = (t >> 6) + 4 * rr;  // 0..31
      float b0 = s[il][2 * m2] * NLOG2E;
      float b1 = s[il][2 * m2 + 1] * NLOG2E;
      uint u = __builtin_bit_cast(uint, __builtin_amdgcn_cvt_pkrtz(b0, b1));
      betaTp[(size_t)(bj * 32 + m2) * NTOK + bi * 64 + il] = u;
    }
  }
}

// ---------------- main ------------------------------------------------------
// 1024 blocks (64 q-rows each), 3 blocks/CU (12 waves). Wave = (i_str, m_str).
// GEMM1 fp8 32x32x16 (S^T in regs), sigmoid, shfl^32 transpose to B-frags,
// GEMM2 f16 32x32x16 (O^T in 64 AGPRs). Pair-reduce epilogue via LDS.
__global__ __launch_bounds__(256, 3) void cos_att_main(
    const unsigned char* __restrict__ x8n, const f16* __restrict__ xhT,
    const uint* __restrict__ betaTp, float* __restrict__ out) {
  __shared__ __align__(16) char smem[49152];  // dbuf: 2 x (sXm8 8K + sXmT 16K)
  int bx = blockIdx.x;
  int bc = bx & 63;  // bc minor: same-bc blocks co-locate per XCD (bx%8 const)
  int qt = bx >> 6;  // 0..15
  int q0 = qt * 64;

  int t = threadIdx.x;
  int lane = t & 63;
  int w = t >> 6;
  int l31 = lane & 31;
  int hi = lane >> 5;
  int i_str = (w >> 1) * 32;
  int m_str = (w & 1) * 32;

  // Xq B-frags (fp8) for this wave's i-strip (16 VGPRs)
  i64 xq8[8];
  {
    const unsigned char* base =
        x8n + ((size_t)bc * NTOK + q0 + i_str + l31) * DDIM + hi * 8;
#pragma unroll
    for (int kk = 0; kk < 8; ++kk) xq8[kk] = *(const i64*)(base + kk * 16);
  }

  auto stage = [&](int mi, int b) {
    int m0 = mi * 64;
    char* ldsm8 = smem + b * 24576;
    char* ldst = ldsm8 + 8192;
    {  // sXm8: 64 rows x 128B fp8, 16B-chunk XOR by (r&7)
      const unsigned char* gb8 = x8n + ((size_t)bc * NTOK + m0) * DDIM;
#pragma unroll
      for (int j = 0; j < 2; ++j) {
        int u = t + 256 * j;
        int r = u >> 3;
        int cp = u & 7;
        const unsigned char* gp =
            gb8 + (size_t)r * DDIM + ((cp ^ (r & 7)) * 16);
        __builtin_amdgcn_global_load_lds((const AS1 uint*)gp,
                                         (AS3 uint*)(ldsm8 + u * 16), 16, 0, 0);
      }
    }
    {  // sXmT: 128 rows x 128B f16, 16B-chunk XOR by (d&7)
      int lr = lane >> 3;
      int cp = lane & 7;
      const f16* gb = xhT + (size_t)bc * DDIM * NTOK + m0;
#pragma unroll
      for (int j = 0; j < 4; ++j) {
        int d = 32 * w + 8 * j + lr;
        int g = cp ^ (d & 7);
        const f16* gp = gb + (size_t)d * NTOK + g * 8;
        __builtin_amdgcn_global_load_lds(
            (const AS1 uint*)gp, (AS3 uint*)(ldst + (32 * w + 8 * j) * 128),
            16, 0, 0);
      }
    }
  };

  stage(0, 0);

  f32x16 o[4];
#pragma unroll
  for (int dt = 0; dt < 4; ++dt)
#pragma unroll
    for (int z = 0; z < 16; ++z) o[dt][z] = 0.f;

  for (int mi = 0; mi < 16; ++mi) {
    int b = mi & 1;
    int m0 = mi * 64;
    __syncthreads();  // buf[b] DMA drained; prev reads of buf[1-b] done

    // beta loads first (oldest vmem), then next-tile DMA
    uint bvp[8];
    {
      const uint* bbase =
          betaTp + (size_t)((m0 + m_str) >> 1) * NTOK + q0 + i_str + l31;
#pragma unroll
      for (int rp = 0; rp < 8; ++rp) {
        int m2l = (rp & 1) + 4 * (rp >> 1) + 2 * hi;
        bvp[rp] = bbase[(size_t)m2l * NTOK];
      }
    }
    if (mi < 15) stage(mi + 1, 1 - b);

    const char* ldsm8 = smem + b * 24576;
    const char* ldst = ldsm8 + 8192;

    // GEMM1 (fp8): S^T[m_str..+31][i_str..+31], K=128
    f32x16 s;
#pragma unroll
    for (int z = 0; z < 16; ++z) s[z] = 0.f;
    {
      int rA = m_str + l31;
      const char* rowA = ldsm8 + rA * 128;
      int rx = rA & 7;
#pragma unroll
      for (int kk = 0; kk < 8; ++kk) {
        i64 a = *(const i64*)(rowA + ((kk ^ rx) * 16) + hi * 8);
        s = __builtin_amdgcn_mfma_f32_32x32x16_fp8_fp8(a, xq8[kk], s, 0, 0, 0);
      }
    }

    // P = sigmoid(beta*cos) packed to f16 pairs
    float pk[8];
#pragma unroll
    for (int rp = 0; rp < 8; ++rp) {
      f16x2v bh = __builtin_bit_cast(f16x2v, bvp[rp]);
      float e0 = __builtin_amdgcn_exp2f((float)bh[0] * s[2 * rp]);
      float e1 = __builtin_amdgcn_exp2f((float)bh[1] * s[2 * rp + 1]);
      float p0 = __builtin_amdgcn_rcpf(1.0f + e0);
      float p1 = __builtin_amdgcn_rcpf(1.0f + e1);
      pk[rp] = __builtin_bit_cast(float, __builtin_amdgcn_cvt_pkrtz(p0, p1));
    }
    // lane^32 exchange -> B-operand fragments for GEMM2
    float qk[8];
#pragma unroll
    for (int rp = 0; rp < 8; ++rp) qk[rp] = __shfl_xor(pk[rp], 32);
    PFrag bt0, bt1;
    bt0.f[0] = hi ? qk[2] : pk[0];
    bt0.f[1] = hi ? qk[3] : pk[1];
    bt0.f[2] = hi ? pk[2] : qk[0];
    bt0.f[3] = hi ? pk[3] : qk[1];
    bt1.f[0] = hi ? qk[6] : pk[4];
    bt1.f[1] = hi ? qk[7] : pk[5];
    bt1.f[2] = hi ? pk[6] : qk[4];
    bt1.f[3] = hi ? pk[7] : qk[5];

    // GEMM2 (f16): O^T[d][i] += XmT . P, K=32 (this wave's m_str half)
#pragma unroll
    for (int dt = 0; dt < 4; ++dt) {
      int d = dt * 32 + l31;
      const char* rowT = ldst + d * 128;
      int dx = d & 7;
      int g0 = (m_str >> 3) + hi;
      f16x8 a0 = *(const f16x8*)(rowT + (g0 ^ dx) * 16);
      f16x8 a1 = *(const f16x8*)(rowT + ((g0 + 2) ^ dx) * 16);
      o[dt] = __builtin_amdgcn_mfma_f32_32x32x16_f16(a0, bt0.h, o[dt], 0, 0, 0);
      o[dt] = __builtin_amdgcn_mfma_f32_32x32x16_f16(a1, bt1.h, o[dt], 0, 0, 0);
    }
  }

  // epilogue: pair-reduce (m_str 0 + 32) + transpose via LDS, coalesced store
  float* sO = (float*)smem;  // [64][132] = 33792 B < 49152
  __syncthreads();
  if ((w & 1) == 0) {
#pragma unroll
    for (int dt = 0; dt < 4; ++dt)
#pragma unroll
      for (int r = 0; r < 16; ++r) {
        int rowl = (r & 3) + 8 * (r >> 2) + 4 * hi;
        sO[(i_str + l31) * 132 + dt * 32 + rowl] = o[dt][r];
      }
  }
  __syncthreads();
  if (w & 1) {
#pragma unroll
    for (int dt = 0; dt < 4; ++dt)
#pragma unroll
      for (int r = 0; r < 16; ++r) {
        int rowl = (r & 3) + 8 * (r >> 2) + 4 * hi;
        sO[(i_str + l31) * 132 + dt * 32 + rowl] += o[dt][r];
      }
  }
  __syncthreads();
  float* og = out + ((size_t)bc * NTOK + q0) * DDIM;
#pragma unroll
  for (int k = 0; k < 8; ++k) {
    int idx = t + 256 * k;
    int row = idx >> 5;
    int c4 = idx & 31;
    *(float4*)(og + (size_t)row * DDIM + c4 * 4) =
        *(const float4*)(sO + row * 132 + c4 * 4);
  }
}

extern "C" void kernel_launch(void* const* d_in, const int* in_sizes, int n_in,
                              void* d_out, int out_size, void* d_ws,
                              size_t ws_size, hipStream_t stream) {
  const float* x = (const float*)d_in[0];
  const float* beta = (const float*)d_in[1];
  float* out = (float*)d_out;

  char* ws = (char*)d_ws;
  unsigned char* x8n = (unsigned char*)ws;  // 8 MB
  f16* xhT = (f16*)(ws + (8 << 20));        // 16 MB
  uint* betaTp = (uint*)(ws + (24 << 20));  // 2 MB

  prep_fused<<<1280, 256, 0, stream>>>(x, beta, x8n, xhT, betaTp);
  cos_att_main<<<1024, 256, 0, stream>>>(x8n, xhT, betaTp, out);
}